// Round 5
// baseline (525.364 us; speedup 1.0000x reference)
//
#include <hip/hip_runtime.h>

#define N_NODES 50000
#define N_EDGES 300000
#define DFEAT 256
#define KCAT 512
#define MT 32          // nodes per block in fused kernel
#define APAD 8         // bf16 row padding: row stride 520*2=1040 B
#define AROW (KCAT + APAD)
#define SCAN_NBLK ((N_NODES + 255) / 256)   // 196
#define NB_PREP 304                          // persistent-kernel grid (well under co-residency)
#define WT_IDS (KCAT * DFEAT)                // 131072 = 1<<17
#define CONV4 (N_NODES * DFEAT / 4)          // 3,200,000 ushort4 units per tensor

typedef __attribute__((ext_vector_type(8))) short bf16x8;
typedef __attribute__((ext_vector_type(8))) unsigned short u16x8;
typedef __attribute__((ext_vector_type(4))) float f32x4;

__device__ __forceinline__ unsigned short f2bf(float f) {
    union { float f; unsigned int u; } c; c.f = f;
    unsigned int r = c.u + 0x7FFF + ((c.u >> 16) & 1);   // round-to-nearest-even
    return (unsigned short)(r >> 16);
}
__device__ __forceinline__ float bf2f(unsigned short u) {
    union { unsigned int i; float f; } c; c.i = ((unsigned int)u) << 16;
    return c.f;
}

// ---------- kernel A: zero the grid-barrier counters ----------
__global__ void k_bzero(int* __restrict__ bar) {
    if (threadIdx.x < 16) bar[threadIdx.x] = 0;
}

// device-scope grid barrier: all gridDim.x blocks rendezvous; target = phase*gridDim.x
__device__ __forceinline__ void gbar(int* bar, int phase) {
    __syncthreads();
    if (threadIdx.x == 0) {
        __threadfence();   // release all prior global writes to device scope
        __hip_atomic_fetch_add(bar, 1, __ATOMIC_ACQ_REL, __HIP_MEMORY_SCOPE_AGENT);
        int target = phase * (int)gridDim.x;
        while (__hip_atomic_load(bar, __ATOMIC_ACQUIRE, __HIP_MEMORY_SCOPE_AGENT) < target) {
            __builtin_amdgcn_s_sleep(2);
        }
    }
    __syncthreads();
}

// ---------- kernel B: persistent prep — zero+wt+conv | hist | scan | scatter ----------
__global__ __launch_bounds__(256, 2)
void k_prep(const int* __restrict__ ei,
            const float* __restrict__ Wl_o, const float* __restrict__ Wr_o,
            const float* __restrict__ Wl_r, const float* __restrict__ Wr_r,
            const float* __restrict__ x_obj, const float* __restrict__ x_rel,
            int* __restrict__ cnt, int* __restrict__ off, int* __restrict__ cursor,
            int* __restrict__ srcs, int* __restrict__ bsum, int* __restrict__ bpre,
            unsigned short* __restrict__ Wb_o, unsigned short* __restrict__ Wb_r,
            ushort4* __restrict__ xb_o, ushort4* __restrict__ xb_r,
            int* __restrict__ bar) {
    __shared__ int slds[256];
    const int bid = blockIdx.x, t = threadIdx.x;
    const int g = bid * 256 + t;
    const int gs = (int)gridDim.x * 256;

    // ---- phase 0: zero cnt ; swizzle weights ; convert features to bf16 ----
    for (int i = g; i < N_NODES; i += gs) cnt[i] = 0;

    for (int id = g; id < 2 * WT_IDS; id += gs) {
        int tz = id >> 17;
        int l  = id & (WT_IDS - 1);
        int j    = l & 7;
        int lane = (l >> 3) & 63;
        int frag = l >> 9;
        int nt   = frag & 15;
        int kb   = frag >> 4;
        int k  = kb * 32 + (lane >> 4) * 8 + j;
        int nn = nt * 16 + (lane & 15);
        const float* Wl = tz ? Wl_r : Wl_o;
        const float* Wr = tz ? Wr_r : Wr_o;
        float v = (k < 256) ? Wl[nn * 256 + k] : Wr[nn * 256 + (k - 256)];
        (tz ? Wb_r : Wb_o)[l] = f2bf(v);
    }

    const float4* xo4 = (const float4*)x_obj;
    const float4* xr4 = (const float4*)x_rel;
    for (int id = g; id < 2 * CONV4; id += gs) {
        int tz = (id >= CONV4);
        int e4 = tz ? id - CONV4 : id;
        float4 v = tz ? xr4[e4] : xo4[e4];
        ushort4 o = make_ushort4(f2bf(v.x), f2bf(v.y), f2bf(v.z), f2bf(v.w));
        (tz ? xb_r : xb_o)[e4] = o;
    }
    gbar(bar, 1);

    // ---- phase 1: histogram of dst ----
    for (int e = g; e < N_EDGES; e += gs) {
        unsigned d = (unsigned)ei[2 * e + 1];
        if (d < (unsigned)N_NODES) atomicAdd(&cnt[d], 1);
    }
    gbar(bar, 2);

    // ---- phase 2: per-block sums (blocks 0..SCAN_NBLK-1) ----
    if (bid < SCAN_NBLK) {
        int i = bid * 256 + t;
        int v = (i < N_NODES) ? cnt[i] : 0;
        #pragma unroll
        for (int d = 32; d; d >>= 1) v += __shfl_down(v, d, 64);
        if ((t & 63) == 0) slds[t >> 6] = v;
        __syncthreads();
        if (t == 0) bsum[bid] = slds[0] + slds[1] + slds[2] + slds[3];
        __syncthreads();
    }
    gbar(bar, 3);

    // ---- phase 3: scan block sums (block 0 only) ----
    if (bid == 0) {
        int v = (t < SCAN_NBLK) ? bsum[t] : 0;
        slds[t] = v;
        __syncthreads();
        for (int d = 1; d < 256; d <<= 1) {
            int u = (t >= d) ? slds[t - d] : 0;
            __syncthreads();
            slds[t] += u;
            __syncthreads();
        }
        if (t < SCAN_NBLK) bpre[t] = slds[t] - v;
        if (t == 255) off[N_NODES] = slds[255];
        __syncthreads();
    }
    gbar(bar, 4);

    // ---- phase 4: per-block exclusive scan -> off, cursor ----
    if (bid < SCAN_NBLK) {
        int i = bid * 256 + t;
        int v = (i < N_NODES) ? cnt[i] : 0;
        slds[t] = v;
        __syncthreads();
        for (int d = 1; d < 256; d <<= 1) {
            int u = (t >= d) ? slds[t - d] : 0;
            __syncthreads();
            slds[t] += u;
            __syncthreads();
        }
        if (i < N_NODES) {
            int ex = bpre[bid] + slds[t] - v;
            off[i] = ex;
            cursor[i] = ex;
        }
        __syncthreads();
    }
    gbar(bar, 5);

    // ---- phase 5: scatter srcs into CSR order ----
    for (int e = g; e < N_EDGES; e += gs) {
        unsigned s = (unsigned)ei[2 * e];
        unsigned d = (unsigned)ei[2 * e + 1];
        if (d < (unsigned)N_NODES && s < (unsigned)N_NODES) {
            unsigned pos = (unsigned)atomicAdd(&cursor[d], 1);
            if (pos < (unsigned)N_EDGES) srcs[pos] = (int)s;
        }
    }
}

// ---------- kernel C: fused aggregation + MFMA GEMM ----------
// Phase 1: half-wave (32 lanes) per node, bf16 feature rows (512 B), 4-deep unroll
//          => 8 gather rows in flight per wave.
__global__ __launch_bounds__(256, 4)
void k_fused(const unsigned short* __restrict__ xb_obj, const unsigned short* __restrict__ xb_rel,
             const unsigned short* __restrict__ Wb_obj, const unsigned short* __restrict__ Wb_rel,
             const float* __restrict__ b_obj, const float* __restrict__ b_rel,
             const int* __restrict__ off, const int* __restrict__ srcs,
             float* __restrict__ out, int n) {
    __shared__ unsigned short A[MT][AROW];     // 32 x 520 bf16 = 33,280 B

    const int tz = blockIdx.y;
    const unsigned short* __restrict__ xb = tz ? xb_rel : xb_obj;
    const unsigned short* __restrict__ Wb = tz ? Wb_rel : Wb_obj;
    const float* __restrict__ bia = tz ? b_rel : b_obj;
    float* __restrict__ outp = out + (size_t)tz * (size_t)N_NODES * DFEAT;

    const int t = threadIdx.x;
    const int node0 = blockIdx.x * MT;

    // ---- phase 1 ----
    const int half = t >> 5;        // 0..7: half-wave id
    const int l32  = t & 31;
    const u16x8* __restrict__ xb8 = (const u16x8*)xb;   // row = 32 u16x8 units (256 bf16)

    for (int q = 0; q < 4; q++) {
        int il = half * 4 + q;                 // 0..31
        int node = node0 + il;
        float a[8] = {0.f, 0.f, 0.f, 0.f, 0.f, 0.f, 0.f, 0.f};
        u16x8 xv = (u16x8){0, 0, 0, 0, 0, 0, 0, 0};
        int eb = 0, ee = 0;
        if (node < n) {
            xv = xb8[(size_t)node * 32 + l32];
            eb = off[node]; ee = off[node + 1];
            if (eb < 0) eb = 0;
            if (ee > N_EDGES) ee = N_EDGES;
            if (ee < eb) ee = eb;
        }
        int e = eb;
        for (; e + 3 < ee; e += 4) {
            unsigned s0 = (unsigned)srcs[e],     s1 = (unsigned)srcs[e + 1];
            unsigned s2 = (unsigned)srcs[e + 2], s3 = (unsigned)srcs[e + 3];
            if (s0 >= (unsigned)n) s0 = 0;
            if (s1 >= (unsigned)n) s1 = 0;
            if (s2 >= (unsigned)n) s2 = 0;
            if (s3 >= (unsigned)n) s3 = 0;
            u16x8 v0 = xb8[(size_t)s0 * 32 + l32];
            u16x8 v1 = xb8[(size_t)s1 * 32 + l32];
            u16x8 v2 = xb8[(size_t)s2 * 32 + l32];
            u16x8 v3 = xb8[(size_t)s3 * 32 + l32];
            #pragma unroll
            for (int j = 0; j < 8; j++)
                a[j] += (bf2f(v0[j]) + bf2f(v1[j])) + (bf2f(v2[j]) + bf2f(v3[j]));
        }
        if (e + 1 < ee) {
            unsigned s0 = (unsigned)srcs[e], s1 = (unsigned)srcs[e + 1];
            if (s0 >= (unsigned)n) s0 = 0;
            if (s1 >= (unsigned)n) s1 = 0;
            u16x8 v0 = xb8[(size_t)s0 * 32 + l32];
            u16x8 v1 = xb8[(size_t)s1 * 32 + l32];
            #pragma unroll
            for (int j = 0; j < 8; j++) a[j] += bf2f(v0[j]) + bf2f(v1[j]);
            e += 2;
        }
        if (e < ee) {
            unsigned s0 = (unsigned)srcs[e];
            if (s0 >= (unsigned)n) s0 = 0;
            u16x8 v0 = xb8[(size_t)s0 * 32 + l32];
            #pragma unroll
            for (int j = 0; j < 8; j++) a[j] += bf2f(v0[j]);
        }
        float inv = 1.0f / fmaxf((float)(ee - eb), 1.0f);
        u16x8 av;
        #pragma unroll
        for (int j = 0; j < 8; j++) av[j] = f2bf(a[j] * inv);
        *(u16x8*)&A[il][l32 * 8]       = av;   // agg in k-cols [0,256)
        *(u16x8*)&A[il][256 + l32 * 8] = xv;   // x   in k-cols [256,512)
    }
    __syncthreads();

    // ---- phase 2: 32x256 MFMA GEMM (unchanged) ----
    const int wave = t >> 6, lane = t & 63;
    const int r0  = (wave & 1) * 16;
    const int nt0 = (wave >> 1) * 8;
    const int lq  = lane >> 4;
    const int lm  = lane & 15;

    f32x4 acc[8];
    #pragma unroll
    for (int ct = 0; ct < 8; ct++) {
        float b = bia[(nt0 + ct) * 16 + lm];
        acc[ct] = (f32x4){b, b, b, b};
    }

    const bf16x8* __restrict__ Wb8 = (const bf16x8*)Wb;
    #pragma unroll
    for (int kb = 0; kb < 16; kb++) {
        bf16x8 af = *(const bf16x8*)&A[r0 + lm][kb * 32 + lq * 8];
        #pragma unroll
        for (int ct = 0; ct < 8; ct++) {
            bf16x8 bf = Wb8[(size_t)(kb * 16 + nt0 + ct) * 64 + lane];
            acc[ct] = __builtin_amdgcn_mfma_f32_16x16x32_bf16(af, bf, acc[ct], 0, 0, 0);
        }
    }

    // ---- writeback: C/D layout col=lane&15, row=quad*4+reg ----
    #pragma unroll
    for (int ct = 0; ct < 8; ct++) {
        int col = (nt0 + ct) * 16 + lm;
        #pragma unroll
        for (int r = 0; r < 4; r++) {
            int node = node0 + r0 + lq * 4 + r;
            if (node < n) outp[((size_t)node << 8) + col] = acc[ct][r];
        }
    }
}

extern "C" void kernel_launch(void* const* d_in, const int* in_sizes, int n_in,
                              void* d_out, int out_size, void* d_ws, size_t ws_size,
                              hipStream_t stream) {
    const float* obj  = (const float*)d_in[0];
    const float* rel  = (const float*)d_in[1];
    const int*   ei   = (const int*)d_in[2];
    const float* Wl_o = (const float*)d_in[3];
    const float* bl_o = (const float*)d_in[4];
    const float* Wr_o = (const float*)d_in[5];
    const float* Wl_r = (const float*)d_in[6];
    const float* bl_r = (const float*)d_in[7];
    const float* Wr_r = (const float*)d_in[8];
    float* out = (float*)d_out;

    char* w = (char*)d_ws;
    size_t o = 0;
    auto alloc = [&](size_t b) { size_t r = o; o += (b + 255) & ~(size_t)255; return r; };
    int*            cnt    = (int*)(w + alloc((size_t)N_NODES * 4));
    int*            off    = (int*)(w + alloc((size_t)(N_NODES + 1) * 4));
    int*            cursor = (int*)(w + alloc((size_t)N_NODES * 4));
    int*            srcs   = (int*)(w + alloc((size_t)N_EDGES * 4));
    int*            bsum   = (int*)(w + alloc(256 * 4));
    int*            bpre   = (int*)(w + alloc(256 * 4));
    int*            bar    = (int*)(w + alloc(256));
    unsigned short* Wb_o   = (unsigned short*)(w + alloc((size_t)KCAT * DFEAT * 2));
    unsigned short* Wb_r   = (unsigned short*)(w + alloc((size_t)KCAT * DFEAT * 2));
    ushort4*        xb_o   = (ushort4*)(w + alloc((size_t)N_NODES * DFEAT * 2));
    ushort4*        xb_r   = (ushort4*)(w + alloc((size_t)N_NODES * DFEAT * 2));

    k_bzero<<<1, 64, 0, stream>>>(bar);
    k_prep<<<NB_PREP, 256, 0, stream>>>(ei, Wl_o, Wr_o, Wl_r, Wr_r, obj, rel,
                                        cnt, off, cursor, srcs, bsum, bpre,
                                        Wb_o, Wb_r, xb_o, xb_r, bar);
    dim3 g((N_NODES + MT - 1) / MT, 2);
    k_fused<<<g, 256, 0, stream>>>((const unsigned short*)xb_o, (const unsigned short*)xb_r,
                                   Wb_o, Wb_r, bl_o, bl_r, off, srcs, out, N_NODES);
}